// Round 7
// baseline (52.139 us; speedup 1.0000x reference)
//
#include <hip/hip_runtime.h>
#include <math.h>

#define NC 80
#define TCOLS 6      // targets: [b, cls, x, y, w, h]
#define OBJB 31      // obj-stream blocks
#define HSIZE 4096   // LDS hash set (16 KB)
#define RPB 15       // rows per block (waves 0..14; wave 15 idle)

// ANCHORS[scale][anchor][wh]
__device__ __constant__ float c_anch[3][3][2] = {
  {{10.f,13.f},{16.f,30.f},{33.f,23.f}},
  {{30.f,61.f},{62.f,45.f},{59.f,119.f}},
  {{116.f,90.f},{156.f,198.f},{373.f,326.f}}
};

// acc layout (floats) — each hot scalar on its own 64 B line
#define ACC_OBJ    0                    // obj background stream sum
#define ACC_CORR   16                   // obj correction sum(-x/cnt)
#define ACC_BOX(s) (32 + 16*(s))
#define ACC_CLS(s) (80 + 16*(s))
#define ACC_NV(s)  (128 + 16*(s))
#define ACC_SEG    176                  // [3*NC sums][3*NC counts] = 480
#define ACC_TICKET 672                  // unsigned ticket, own line
#define ACC_TOTAL  688                  // floats (2752 B memset)

// fast transcendentals: v_exp/v_log/v_sqrt; abs err ~1e-6 << 0.47 threshold
__device__ __forceinline__ float fbce0(float x) {   // bce(x,0)
  return fmaxf(x, 0.f) + __logf(1.f + __expf(-fabsf(x)));
}
__device__ __forceinline__ float fbce(float x, float t) {
  return fmaxf(x, 0.f) - x * t + __logf(1.f + __expf(-fabsf(x)));
}
__device__ __forceinline__ float ffocal(float x, float t) {
  float ce = fbce(x, t);
  float u  = 1.f - __expf(-ce);
  return u * __builtin_amdgcn_sqrtf(u) * ce;        // (1-e^-ce)^1.5 * ce
}

// blocks [0,RB):      rows — 15 rows/block, one 64-lane wave per (s,n,a) row
// blocks [RB,RB+OBJB): obj background stream -> atomicAdd into ACC_OBJ
// block  RB+OBJB:     obj correction, LDS hash-set dedup (bce(x,1)-bce(x,0) = -x)
// epilogue:           atomic ticket; last block finalizes out[] (no extra launch)
__global__ __launch_bounds__(1024, 8)
void k_all(const float* __restrict__ p0, const float* __restrict__ p1,
           const float* __restrict__ p2, const float* __restrict__ tgt,
           int N, int B, int RB, float* __restrict__ acc,
           float* __restrict__ out) {
  const int bid = blockIdx.x;
  const int tid = threadIdx.x;

  __shared__ int   htab[HSIZE];
  __shared__ float l_box[3], l_cls[3], l_nv[3];
  __shared__ float red[16];
  __shared__ unsigned s_rank;

  if (bid < RB) {
    // ---------------- rows role ----------------
    if (tid < 3) { l_box[tid]=0.f; l_cls[tid]=0.f; l_nv[tid]=0.f; }
    __syncthreads();
    int wv   = tid >> 6;
    int lane = tid & 63;
    int row  = bid * RPB + wv;
    int nrows = 9 * N;
    if (wv < RPB && row < nrows) {
      int rps = N * 3;
      int s   = row / rps;
      int rem = row - s * rps;
      int n   = rem / 3;
      int a   = rem - n * 3;
      int w   = (s == 0) ? 80 : ((s == 1) ? 40 : 20);
      int hw  = w * w;
      const float* pred = (s == 0) ? p0 : ((s == 1) ? p1 : p2);
      float fw = (float)w;
      float gx = tgt[n*TCOLS + 2] * fw, gy = tgt[n*TCOLS + 3] * fw;
      if (gx >= 0.f && gx < fw && gy >= 0.f && gy < fw) {   // wave-uniform
        float gw = tgt[n*TCOLS + 4] * fw, gh = tgt[n*TCOLS + 5] * fw;
        int gi  = min(max((int)floorf(gx), 0), w - 1);
        int gj  = min(max((int)floorf(gy), 0), w - 1);
        int b   = min(max((int)tgt[n*TCOLS + 0], 0), B - 1);
        int cls = min(max((int)tgt[n*TCOLS + 1], 0), NC - 1);
        size_t base = (size_t)(b*255 + a*85) * hw + (size_t)(gj*w + gi);

        // issue all global loads up-front (MLP)
        float x0  = pred[base + (size_t)(5 + lane) * hw];          // cls c = lane
        float x1  = pred[base + (size_t)(69 + (lane & 15)) * hw];  // cls 64+(lane&15)
        float bxv = (lane < 4) ? pred[base + (size_t)lane * hw] : 0.f;

        float rs = ffocal(x0, (lane == cls) ? 1.f : 0.f);
        if (lane < 16) rs += ffocal(x1, ((64 + lane) == cls) ? 1.f : 0.f);
        for (int off = 32; off > 0; off >>= 1) rs += __shfl_xor(rs, off, 64);

        float bx = __shfl(bxv, 0, 64), by = __shfl(bxv, 1, 64);
        float bw = __shfl(bxv, 2, 64), bh = __shfl(bxv, 3, 64);
        if (lane == 0) {
          float sx = 1.f/(1.f + __expf(-bx));
          float sy = 1.f/(1.f + __expf(-by));
          float sw = 1.f/(1.f + __expf(-bw));
          float sh = 1.f/(1.f + __expf(-bh));
          float px = sx*2.f - 0.5f, py = sy*2.f - 0.5f;
          float aw = c_anch[s][a][0], ah = c_anch[s][a][1];
          float pw = (sw*2.f)*(sw*2.f)*aw, ph = (sh*2.f)*(sh*2.f)*ah;
          float txf = gx - floorf(gx), tyf = gy - floorf(gy);
          // iou_cxcywh replicated (eps on heights + union only)
          float b1x1 = px - pw*0.5f, b1x2 = px + pw*0.5f;
          float b1y1 = py - ph*0.5f, b1y2 = py + ph*0.5f;
          float b2x1 = txf - gw*0.5f, b2x2 = txf + gw*0.5f;
          float b2y1 = tyf - gh*0.5f, b2y2 = tyf + gh*0.5f;
          float iw = fmaxf(fminf(b1x2, b2x2) - fmaxf(b1x1, b2x1), 0.f);
          float ih = fmaxf(fminf(b1y2, b2y2) - fmaxf(b1y1, b2y1), 0.f);
          float inter = iw * ih;
          float w1 = b1x2 - b1x1, h1 = b1y2 - b1y1 + 1e-7f;
          float w2 = b2x2 - b2x1, h2 = b2y2 - b2y1 + 1e-7f;
          float uni = w1*h1 + w2*h2 - inter + 1e-7f;
          float iou = inter / uni;

          atomicAdd(&l_box[s], 1.f - iou);
          atomicAdd(&l_cls[s], rs);
          atomicAdd(&l_nv[s],  1.f);
          atomicAdd(&acc[ACC_SEG +        s*NC + cls], rs);
          atomicAdd(&acc[ACC_SEG + 3*NC + s*NC + cls], 1.f);
        }
      }
    }
    __syncthreads();
    if (tid < 3) {
      int s = tid; float v;
      v = l_box[s]; if (v != 0.f) atomicAdd(&acc[ACC_BOX(s)], v);
      v = l_cls[s]; if (v != 0.f) atomicAdd(&acc[ACC_CLS(s)], v);
      v = l_nv [s]; if (v != 0.f) atomicAdd(&acc[ACC_NV (s)], v);
    }
  } else if (bid < RB + OBJB) {
    // ---------------- obj background stream role ----------------
    const int ob = bid - RB;
    const int n0 = B*3*6400, n1 = B*3*1600, n2 = B*3*400;
    const int total4 = (n0 + n1 + n2) >> 2;
    const float i0 = 1.f/(float)n0, i1 = 1.f/(float)n1, i2 = 1.f/(float)n2;
    float local = 0.f;
    for (int i = ob * 1024 + tid; i < total4; i += OBJB * 1024) {
      int e = i << 2;
      const float* pred; int idx, hw; float inv;
      if (e < n0)         { pred = p0; idx = e;           hw = 6400; inv = i0; }
      else if (e < n0+n1) { pred = p1; idx = e - n0;      hw = 1600; inv = i1; }
      else                { pred = p2; idx = e - n0 - n1; hw = 400;  inv = i2; }
      int ba = idx / hw, pix = idx - ba * hw;     // pix..pix+3 in-plane (hw%4==0)
      int b = ba / 3, a = ba - b * 3;
      const float4 x4 = *(const float4*)&pred[(size_t)(b*255 + a*85 + 4) * hw + pix];
      local += (fbce0(x4.x) + fbce0(x4.y) + fbce0(x4.z) + fbce0(x4.w)) * inv;
    }
    for (int off = 32; off > 0; off >>= 1) local += __shfl_xor(local, off, 64);
    if ((tid & 63) == 0) red[tid >> 6] = local;
    __syncthreads();
    if (tid == 0) {
      float t = 0.f;
      for (int k = 0; k < 16; ++k) t += red[k];
      atomicAdd(&acc[ACC_OBJ], t);
    }
  } else {
    // -------- correction role: LDS hash-set dedup, O(M) --------
    for (int k = tid; k < HSIZE; k += 1024) htab[k] = -1;
    __syncthreads();
    int M = 3 * N;
    float corr = 0.f;
    for (int i = tid; i < M; i += 1024) {
      int s = i / N, n = i - s * N;
      int w = (s == 0) ? 80 : ((s == 1) ? 40 : 20);
      float fw = (float)w;
      float gx = tgt[n*TCOLS + 2] * fw, gy = tgt[n*TCOLS + 3] * fw;
      if (gx >= 0.f && gx < fw && gy >= 0.f && gy < fw) {
        int hw = w * w;
        int gi = min(max((int)floorf(gx), 0), w - 1);
        int gj = min(max((int)floorf(gy), 0), w - 1);
        int b  = min(max((int)tgt[n*TCOLS + 0], 0), B - 1);
        int idx = b * hw + gj * w + gi;            // < 102400 < 2^17
        int key = (s << 17) | idx;
        unsigned h = ((unsigned)key * 2654435761u) >> 20;
        bool owner = false;
        for (;;) {
          int old = atomicCAS(&htab[h & (HSIZE-1)], -1, key);
          if (old == -1)  { owner = true; break; }
          if (old == key) { break; }
          ++h;
        }
        if (owner) {   // all 3 anchors of this distinct (s,b,cell)
          const float* pred = (s == 0) ? p0 : ((s == 1) ? p1 : p2);
          int cell = idx - b * hw;
          float inv = 1.f / (float)(B * 3 * hw);
          float sum = pred[(size_t)(b*255 +   4) * hw + cell]
                    + pred[(size_t)(b*255 +  89) * hw + cell]
                    + pred[(size_t)(b*255 + 174) * hw + cell];
          corr -= sum * inv;              // bce(x,1)-bce(x,0) = -x
        }
      }
    }
    for (int off = 32; off > 0; off >>= 1) corr += __shfl_xor(corr, off, 64);
    if ((tid & 63) == 0) red[tid >> 6] = corr;
    __syncthreads();
    if (tid == 0) {
      float t = 0.f;
      for (int k = 0; k < 16; ++k) t += red[k];
      atomicAdd(&acc[ACC_CORR], t);
    }
  }

  // ---------------- ticket epilogue: last block finalizes ----------------
  __syncthreads();
  if (tid == 0) {
    __threadfence();   // drain this block's atomics to coherence point
    s_rank = atomicAdd((unsigned int*)&acc[ACC_TICKET], 1u);
  }
  __syncthreads();
  if (s_rank != (unsigned)(gridDim.x - 1)) return;

  __threadfence();
  #define AL(i) atomicAdd(&acc[(i)], 0.0f)   // coherent read (same path as writers)
  if (tid == 0) {
    float lo = AL(ACC_OBJ) + AL(ACC_CORR);
    float lb = 0.f, lc = 0.f;
    for (int s = 0; s < 3; ++s) {
      float nv  = AL(ACC_NV(s));
      float nvm = fmaxf(nv, 1.f);
      if (nv > 0.f) {
        lb += AL(ACC_BOX(s)) / nvm * 7.5f;                 // BOX_GAIN
        lc += AL(ACC_CLS(s)) / (nvm * (float)NC) * 0.5f;   // CLS_GAIN
      }
    }
    out[0] = lb + lc + lo;
    out[1] = lb;
    out[2] = lc;
    out[3] = lo;
  }
  if (tid < NC) {
    float pc = 0.f;
    for (int s = 0; s < 3; ++s) {
      float cnt = AL(ACC_SEG + 3*NC + s*NC + tid);
      if (cnt > 0.f)
        pc += AL(ACC_SEG + s*NC + tid) / (fmaxf(cnt, 1.f) * (float)NC) * 0.5f;
    }
    out[4 + tid] = pc;
  }
  #undef AL
}

extern "C" void kernel_launch(void* const* d_in, const int* in_sizes, int n_in,
                              void* d_out, int out_size, void* d_ws, size_t ws_size,
                              hipStream_t stream) {
  const float* p0  = (const float*)d_in[0];
  const float* p1  = (const float*)d_in[1];
  const float* p2  = (const float*)d_in[2];
  const float* tgt = (const float*)d_in[3];
  int N = in_sizes[3] / TCOLS;             // 800 targets
  int B = in_sizes[0] / (255 * 6400);      // 16
  float* out = (float*)d_out;
  float* acc = (float*)d_ws;

  int nrows = 9 * N;                       // 7200
  int RB = (nrows + RPB - 1) / RPB;        // 480 rows-blocks
  int grid = RB + OBJB + 1;                // 512 = 2 blocks/CU exactly

  hipMemsetAsync(acc, 0, ACC_TOTAL * sizeof(float), stream);
  k_all<<<grid, 1024, 0, stream>>>(p0, p1, p2, tgt, N, B, RB, acc, out);
}

// Round 8
// 50.497 us; speedup vs baseline: 1.0325x; 1.0325x over previous
//
#include <hip/hip_runtime.h>
#include <math.h>

#define NC 80
#define TCOLS 6      // targets: [b, cls, x, y, w, h]
#define OBJB 31      // obj-stream blocks
#define HSIZE 4096   // LDS hash set (16 KB)
#define RPB 15       // rows per block (waves 0..14; wave 15 idle)

// ANCHORS[scale][anchor][wh]
__device__ __constant__ float c_anch[3][3][2] = {
  {{10.f,13.f},{16.f,30.f},{33.f,23.f}},
  {{30.f,61.f},{62.f,45.f},{59.f,119.f}},
  {{116.f,90.f},{156.f,198.f},{373.f,326.f}}
};

// acc layout (floats) — each hot scalar on its own 64 B line
#define ACC_OBJ    0                    // obj background stream sum
#define ACC_CORR   16                   // obj correction sum(-x/cnt)
#define ACC_BOX(s) (32 + 16*(s))
#define ACC_CLS(s) (80 + 16*(s))
#define ACC_NV(s)  (128 + 16*(s))
#define ACC_SEG    176                  // [3*NC sums][3*NC counts] = 480
#define ACC_TICKET 672                  // unsigned ticket, own line
#define ACC_TOTAL  688                  // floats

// fast transcendentals: v_exp/v_log/v_sqrt; abs err ~1e-6 << 0.47 threshold
__device__ __forceinline__ float fbce0(float x) {   // bce(x,0)
  return fmaxf(x, 0.f) + __logf(1.f + __expf(-fabsf(x)));
}
__device__ __forceinline__ float fbce(float x, float t) {
  return fmaxf(x, 0.f) - x * t + __logf(1.f + __expf(-fabsf(x)));
}
__device__ __forceinline__ float ffocal(float x, float t) {
  float ce = fbce(x, t);
  float u  = 1.f - __expf(-ce);
  return u * __builtin_amdgcn_sqrtf(u) * ce;        // (1-e^-ce)^1.5 * ce
}

__global__ void k_init(float* __restrict__ acc) {
  int i = threadIdx.x;
  for (int k = i; k < ACC_TOTAL; k += 256) acc[k] = 0.f;
}

// blocks [0,RB):       rows — RPB rows/block, one 64-lane wave per (s,n,a) row
// blocks [RB,RB+OBJB): obj background stream -> atomicAdd into ACC_OBJ
// block  RB+OBJB:      obj correction, LDS hash-set dedup (bce(x,1)-bce(x,0) = -x)
// epilogue:            atomic ticket; last block finalizes out[] (no extra launch)
__global__ __launch_bounds__(1024, 8)
void k_all(const float* __restrict__ p0, const float* __restrict__ p1,
           const float* __restrict__ p2, const float* __restrict__ tgt,
           int N, int B, int RB, float* __restrict__ acc,
           float* __restrict__ out) {
  const int bid = blockIdx.x;
  const int tid = threadIdx.x;

  __shared__ int   htab[HSIZE];
  __shared__ float l_box[3], l_cls[3], l_nv[3];
  __shared__ float red[16];
  __shared__ unsigned s_rank;

  if (bid < RB) {
    // ---------------- rows role ----------------
    if (tid < 3) { l_box[tid]=0.f; l_cls[tid]=0.f; l_nv[tid]=0.f; }
    __syncthreads();
    int wv   = tid >> 6;
    int lane = tid & 63;
    int row  = bid * RPB + wv;
    int nrows = 9 * N;
    if (wv < RPB && row < nrows) {
      int rps = N * 3;
      int s   = row / rps;
      int rem = row - s * rps;
      int n   = rem / 3;
      int a   = rem - n * 3;
      int w   = (s == 0) ? 80 : ((s == 1) ? 40 : 20);
      int hw  = w * w;
      const float* pred = (s == 0) ? p0 : ((s == 1) ? p1 : p2);
      float fw = (float)w;
      float gx = tgt[n*TCOLS + 2] * fw, gy = tgt[n*TCOLS + 3] * fw;
      if (gx >= 0.f && gx < fw && gy >= 0.f && gy < fw) {   // wave-uniform
        float gw = tgt[n*TCOLS + 4] * fw, gh = tgt[n*TCOLS + 5] * fw;
        int gi  = min(max((int)floorf(gx), 0), w - 1);
        int gj  = min(max((int)floorf(gy), 0), w - 1);
        int b   = min(max((int)tgt[n*TCOLS + 0], 0), B - 1);
        int cls = min(max((int)tgt[n*TCOLS + 1], 0), NC - 1);
        size_t base = (size_t)(b*255 + a*85) * hw + (size_t)(gj*w + gi);

        // issue all global loads up-front (MLP); predicate dup/extra lanes
        float x0  = pred[base + (size_t)(5 + lane) * hw];                  // cls c = lane
        float x1  = (lane < 16) ? pred[base + (size_t)(69 + lane) * hw] : 0.f; // cls 64+lane
        float bxv = (lane < 4)  ? pred[base + (size_t)lane * hw] : 0.f;

        float rs = ffocal(x0, (lane == cls) ? 1.f : 0.f);
        if (lane < 16) rs += ffocal(x1, ((64 + lane) == cls) ? 1.f : 0.f);
        for (int off = 32; off > 0; off >>= 1) rs += __shfl_xor(rs, off, 64);

        float bx = __shfl(bxv, 0, 64), by = __shfl(bxv, 1, 64);
        float bw = __shfl(bxv, 2, 64), bh = __shfl(bxv, 3, 64);
        if (lane == 0) {
          float sx = 1.f/(1.f + __expf(-bx));
          float sy = 1.f/(1.f + __expf(-by));
          float sw = 1.f/(1.f + __expf(-bw));
          float sh = 1.f/(1.f + __expf(-bh));
          float px = sx*2.f - 0.5f, py = sy*2.f - 0.5f;
          float aw = c_anch[s][a][0], ah = c_anch[s][a][1];
          float pw = (sw*2.f)*(sw*2.f)*aw, ph = (sh*2.f)*(sh*2.f)*ah;
          float txf = gx - floorf(gx), tyf = gy - floorf(gy);
          // iou_cxcywh replicated (eps on heights + union only)
          float b1x1 = px - pw*0.5f, b1x2 = px + pw*0.5f;
          float b1y1 = py - ph*0.5f, b1y2 = py + ph*0.5f;
          float b2x1 = txf - gw*0.5f, b2x2 = txf + gw*0.5f;
          float b2y1 = tyf - gh*0.5f, b2y2 = tyf + gh*0.5f;
          float iw = fmaxf(fminf(b1x2, b2x2) - fmaxf(b1x1, b2x1), 0.f);
          float ih = fmaxf(fminf(b1y2, b2y2) - fmaxf(b1y1, b2y1), 0.f);
          float inter = iw * ih;
          float w1 = b1x2 - b1x1, h1 = b1y2 - b1y1 + 1e-7f;
          float w2 = b2x2 - b2x1, h2 = b2y2 - b2y1 + 1e-7f;
          float uni = w1*h1 + w2*h2 - inter + 1e-7f;
          float iou = inter / uni;

          atomicAdd(&l_box[s], 1.f - iou);
          atomicAdd(&l_cls[s], rs);
          atomicAdd(&l_nv[s],  1.f);
          atomicAdd(&acc[ACC_SEG +        s*NC + cls], rs);
          atomicAdd(&acc[ACC_SEG + 3*NC + s*NC + cls], 1.f);
        }
      }
    }
    __syncthreads();
    if (tid < 3) {
      int s = tid; float v;
      v = l_box[s]; if (v != 0.f) atomicAdd(&acc[ACC_BOX(s)], v);
      v = l_cls[s]; if (v != 0.f) atomicAdd(&acc[ACC_CLS(s)], v);
      v = l_nv [s]; if (v != 0.f) atomicAdd(&acc[ACC_NV (s)], v);
    }
  } else if (bid < RB + OBJB) {
    // ---------------- obj background stream role ----------------
    const int ob = bid - RB;
    const int n0 = B*3*6400, n1 = B*3*1600, n2 = B*3*400;
    const int total4 = (n0 + n1 + n2) >> 2;
    const float i0 = 1.f/(float)n0, i1 = 1.f/(float)n1, i2 = 1.f/(float)n2;
    float local = 0.f;
    for (int i = ob * 1024 + tid; i < total4; i += OBJB * 1024) {
      int e = i << 2;
      const float* pred; int idx, hw; float inv;
      if (e < n0)         { pred = p0; idx = e;           hw = 6400; inv = i0; }
      else if (e < n0+n1) { pred = p1; idx = e - n0;      hw = 1600; inv = i1; }
      else                { pred = p2; idx = e - n0 - n1; hw = 400;  inv = i2; }
      int ba = idx / hw, pix = idx - ba * hw;     // pix..pix+3 in-plane (hw%4==0)
      int b = ba / 3, a = ba - b * 3;
      const float4 x4 = *(const float4*)&pred[(size_t)(b*255 + a*85 + 4) * hw + pix];
      local += (fbce0(x4.x) + fbce0(x4.y) + fbce0(x4.z) + fbce0(x4.w)) * inv;
    }
    for (int off = 32; off > 0; off >>= 1) local += __shfl_xor(local, off, 64);
    if ((tid & 63) == 0) red[tid >> 6] = local;
    __syncthreads();
    if (tid == 0) {
      float t = 0.f;
      for (int k = 0; k < 16; ++k) t += red[k];
      atomicAdd(&acc[ACC_OBJ], t);
    }
  } else {
    // -------- correction role: LDS hash-set dedup, O(M) --------
    for (int k = tid; k < HSIZE; k += 1024) htab[k] = -1;
    __syncthreads();
    int M = 3 * N;
    float corr = 0.f;
    for (int i = tid; i < M; i += 1024) {
      int s = i / N, n = i - s * N;
      int w = (s == 0) ? 80 : ((s == 1) ? 40 : 20);
      float fw = (float)w;
      float gx = tgt[n*TCOLS + 2] * fw, gy = tgt[n*TCOLS + 3] * fw;
      if (gx >= 0.f && gx < fw && gy >= 0.f && gy < fw) {
        int hw = w * w;
        int gi = min(max((int)floorf(gx), 0), w - 1);
        int gj = min(max((int)floorf(gy), 0), w - 1);
        int b  = min(max((int)tgt[n*TCOLS + 0], 0), B - 1);
        int idx = b * hw + gj * w + gi;            // < 102400 < 2^17
        int key = (s << 17) | idx;
        unsigned h = ((unsigned)key * 2654435761u) >> 20;
        bool owner = false;
        for (;;) {
          int old = atomicCAS(&htab[h & (HSIZE-1)], -1, key);
          if (old == -1)  { owner = true; break; }
          if (old == key) { break; }
          ++h;
        }
        if (owner) {   // all 3 anchors of this distinct (s,b,cell)
          const float* pred = (s == 0) ? p0 : ((s == 1) ? p1 : p2);
          int cell = idx - b * hw;
          float inv = 1.f / (float)(B * 3 * hw);
          float sum = pred[(size_t)(b*255 +   4) * hw + cell]
                    + pred[(size_t)(b*255 +  89) * hw + cell]
                    + pred[(size_t)(b*255 + 174) * hw + cell];
          corr -= sum * inv;              // bce(x,1)-bce(x,0) = -x
        }
      }
    }
    for (int off = 32; off > 0; off >>= 1) corr += __shfl_xor(corr, off, 64);
    if ((tid & 63) == 0) red[tid >> 6] = corr;
    __syncthreads();
    if (tid == 0) {
      float t = 0.f;
      for (int k = 0; k < 16; ++k) t += red[k];
      atomicAdd(&acc[ACC_CORR], t);
    }
  }

  // ---------------- ticket epilogue: last block finalizes ----------------
  __syncthreads();
  if (tid == 0) {
    __threadfence();   // order this block's atomics before the ticket
    s_rank = atomicAdd((unsigned int*)&acc[ACC_TICKET], 1u);
  }
  __syncthreads();
  if (s_rank != (unsigned)(gridDim.x - 1)) return;

  __threadfence();
  #define AL(i) atomicAdd(&acc[(i)], 0.0f)   // coherent read (same path as writers)
  if (tid == 0) {
    float lo = AL(ACC_OBJ) + AL(ACC_CORR);
    float lb = 0.f, lc = 0.f;
    for (int s = 0; s < 3; ++s) {
      float nv  = AL(ACC_NV(s));
      float nvm = fmaxf(nv, 1.f);
      if (nv > 0.f) {
        lb += AL(ACC_BOX(s)) / nvm * 7.5f;                 // BOX_GAIN
        lc += AL(ACC_CLS(s)) / (nvm * (float)NC) * 0.5f;   // CLS_GAIN
      }
    }
    out[0] = lb + lc + lo;
    out[1] = lb;
    out[2] = lc;
    out[3] = lo;
  }
  if (tid < NC) {
    float pc = 0.f;
    for (int s = 0; s < 3; ++s) {
      float cnt = AL(ACC_SEG + 3*NC + s*NC + tid);
      if (cnt > 0.f)
        pc += AL(ACC_SEG + s*NC + tid) / (fmaxf(cnt, 1.f) * (float)NC) * 0.5f;
    }
    out[4 + tid] = pc;
  }
  #undef AL
}

extern "C" void kernel_launch(void* const* d_in, const int* in_sizes, int n_in,
                              void* d_out, int out_size, void* d_ws, size_t ws_size,
                              hipStream_t stream) {
  const float* p0  = (const float*)d_in[0];
  const float* p1  = (const float*)d_in[1];
  const float* p2  = (const float*)d_in[2];
  const float* tgt = (const float*)d_in[3];
  int N = in_sizes[3] / TCOLS;             // 800 targets
  int B = in_sizes[0] / (255 * 6400);      // 16
  float* out = (float*)d_out;
  float* acc = (float*)d_ws;

  int nrows = 9 * N;                       // 7200
  int RB = (nrows + RPB - 1) / RPB;        // 480 rows-blocks
  int grid = RB + OBJB + 1;                // 512 = 2 blocks/CU exactly

  k_init<<<1, 256, 0, stream>>>(acc);
  k_all <<<grid, 1024, 0, stream>>>(p0, p1, p2, tgt, N, B, RB, acc, out);
}

// Round 9
// 41.870 us; speedup vs baseline: 1.2453x; 1.2060x over previous
//
#include <hip/hip_runtime.h>
#include <math.h>

#define NC 80
#define TCOLS 6      // targets: [b, cls, x, y, w, h]
#define OBJ_BLOCKS 61
#define HSIZE 4096   // LDS hash set (16 KB)

// ANCHORS[scale][anchor][wh]
__device__ __constant__ float c_anch[3][3][2] = {
  {{10.f,13.f},{16.f,30.f},{33.f,23.f}},
  {{30.f,61.f},{62.f,45.f},{59.f,119.f}},
  {{116.f,90.f},{156.f,198.f},{373.f,326.f}}
};

// acc layout (floats) — each hot scalar on its own 64 B line
#define ACC_CORR   0                    // obj correction sum(-x/cnt), single writer
#define ACC_BOX(s) (16 + 16*(s))
#define ACC_CLS(s) (64 + 16*(s))
#define ACC_NV(s)  (112 + 16*(s))
#define ACC_SEG    160                  // [3*NC sums][3*NC counts]
#define ACC_TOTAL  (160 + 6*NC)         // 640 floats

// fast transcendentals: v_exp/v_log/v_sqrt; abs err ~1e-6 << 0.47 threshold
__device__ __forceinline__ float fbce0(float x) {   // bce(x,0)
  return fmaxf(x, 0.f) + __logf(1.f + __expf(-fabsf(x)));
}
__device__ __forceinline__ float fbce(float x, float t) {
  return fmaxf(x, 0.f) - x * t + __logf(1.f + __expf(-fabsf(x)));
}
__device__ __forceinline__ float ffocal(float x, float t) {
  float ce = fbce(x, t);
  float u  = 1.f - __expf(-ce);
  return u * __builtin_amdgcn_sqrtf(u) * ce;        // (1-e^-ce)^1.5 * ce
}

__global__ void k_init(float* __restrict__ acc) {
  for (int k = threadIdx.x; k < ACC_TOTAL; k += 256) acc[k] = 0.f;
}

// blocks [0, RB):       rows — one 64-lane wave per (scale,target,anchor), 16/block
// blocks [RB, RB+OBJ):  obj background stream -> plain per-block partial stores
// block  RB+OBJ:        obj correction, LDS hash-set dedup (bce(x,1)-bce(x,0) = -x)
__global__ __launch_bounds__(1024, 8)
void k_fused(const float* __restrict__ p0, const float* __restrict__ p1,
             const float* __restrict__ p2, const float* __restrict__ tgt,
             int N, int B, int RB, float* __restrict__ acc,
             float* __restrict__ partial) {
  const int bid = blockIdx.x;
  const int tid = threadIdx.x;

  if (bid < RB) {
    // ---------------- rows role ----------------
    __shared__ float l_box[3], l_cls[3], l_nv[3];
    if (tid < 3) { l_box[tid]=0.f; l_cls[tid]=0.f; l_nv[tid]=0.f; }
    __syncthreads();
    int row   = bid * 16 + (tid >> 6);
    int lane  = tid & 63;
    int nrows = 9 * N;
    if (row < nrows) {
      int rps = N * 3;
      int s   = row / rps;
      int rem = row - s * rps;
      int n   = rem / 3;
      int a   = rem - n * 3;
      int w   = (s == 0) ? 80 : ((s == 1) ? 40 : 20);
      int hw  = w * w;
      const float* pred = (s == 0) ? p0 : ((s == 1) ? p1 : p2);
      float fw = (float)w;
      float gx = tgt[n*TCOLS + 2] * fw, gy = tgt[n*TCOLS + 3] * fw;
      if (gx >= 0.f && gx < fw && gy >= 0.f && gy < fw) {   // wave-uniform
        float gw = tgt[n*TCOLS + 4] * fw, gh = tgt[n*TCOLS + 5] * fw;
        int gi  = min(max((int)floorf(gx), 0), w - 1);
        int gj  = min(max((int)floorf(gy), 0), w - 1);
        int b   = min(max((int)tgt[n*TCOLS + 0], 0), B - 1);
        int cls = min(max((int)tgt[n*TCOLS + 1], 0), NC - 1);
        size_t base = (size_t)(b*255 + a*85) * hw + (size_t)(gj*w + gi);

        // issue all global loads up-front (MLP); predicate extra lanes
        float x0  = pred[base + (size_t)(5 + lane) * hw];                      // cls c = lane
        float x1  = (lane < 16) ? pred[base + (size_t)(69 + lane) * hw] : 0.f; // cls 64+lane
        float bxv = (lane < 4)  ? pred[base + (size_t)lane * hw] : 0.f;

        float rs = ffocal(x0, (lane == cls) ? 1.f : 0.f);
        if (lane < 16) rs += ffocal(x1, ((64 + lane) == cls) ? 1.f : 0.f);
        for (int off = 32; off > 0; off >>= 1) rs += __shfl_xor(rs, off, 64);

        float bx = __shfl(bxv, 0, 64), by = __shfl(bxv, 1, 64);
        float bw = __shfl(bxv, 2, 64), bh = __shfl(bxv, 3, 64);
        if (lane == 0) {
          float sx = 1.f/(1.f + __expf(-bx));
          float sy = 1.f/(1.f + __expf(-by));
          float sw = 1.f/(1.f + __expf(-bw));
          float sh = 1.f/(1.f + __expf(-bh));
          float px = sx*2.f - 0.5f, py = sy*2.f - 0.5f;
          float aw = c_anch[s][a][0], ah = c_anch[s][a][1];
          float pw = (sw*2.f)*(sw*2.f)*aw, ph = (sh*2.f)*(sh*2.f)*ah;
          float txf = gx - floorf(gx), tyf = gy - floorf(gy);
          // iou_cxcywh replicated (eps on heights + union only)
          float b1x1 = px - pw*0.5f, b1x2 = px + pw*0.5f;
          float b1y1 = py - ph*0.5f, b1y2 = py + ph*0.5f;
          float b2x1 = txf - gw*0.5f, b2x2 = txf + gw*0.5f;
          float b2y1 = tyf - gh*0.5f, b2y2 = tyf + gh*0.5f;
          float iw = fmaxf(fminf(b1x2, b2x2) - fmaxf(b1x1, b2x1), 0.f);
          float ih = fmaxf(fminf(b1y2, b2y2) - fmaxf(b1y1, b2y1), 0.f);
          float inter = iw * ih;
          float w1 = b1x2 - b1x1, h1 = b1y2 - b1y1 + 1e-7f;
          float w2 = b2x2 - b2x1, h2 = b2y2 - b2y1 + 1e-7f;
          float uni = w1*h1 + w2*h2 - inter + 1e-7f;
          float iou = inter / uni;

          atomicAdd(&l_box[s], 1.f - iou);
          atomicAdd(&l_cls[s], rs);
          atomicAdd(&l_nv[s],  1.f);
          atomicAdd(&acc[ACC_SEG +        s*NC + cls], rs);
          atomicAdd(&acc[ACC_SEG + 3*NC + s*NC + cls], 1.f);
        }
      }
    }
    __syncthreads();
    if (tid < 3) {
      int s = tid; float v;
      v = l_box[s]; if (v != 0.f) atomicAdd(&acc[ACC_BOX(s)], v);
      v = l_cls[s]; if (v != 0.f) atomicAdd(&acc[ACC_CLS(s)], v);
      v = l_nv [s]; if (v != 0.f) atomicAdd(&acc[ACC_NV (s)], v);
    }
  } else if (bid < RB + OBJ_BLOCKS) {
    // ---------------- obj background stream role ----------------
    const int ob = bid - RB;
    const int n0 = B*3*6400, n1 = B*3*1600, n2 = B*3*400;
    const int total4 = (n0 + n1 + n2) >> 2;
    const float i0 = 1.f/(float)n0, i1 = 1.f/(float)n1, i2 = 1.f/(float)n2;
    float local = 0.f;
    for (int i = ob * 1024 + tid; i < total4; i += OBJ_BLOCKS * 1024) {
      int e = i << 2;
      const float* pred; int idx, hw; float inv;
      if (e < n0)         { pred = p0; idx = e;           hw = 6400; inv = i0; }
      else if (e < n0+n1) { pred = p1; idx = e - n0;      hw = 1600; inv = i1; }
      else                { pred = p2; idx = e - n0 - n1; hw = 400;  inv = i2; }
      int ba = idx / hw, pix = idx - ba * hw;     // pix..pix+3 in-plane (hw%4==0)
      int b = ba / 3, a = ba - b * 3;
      const float4 x4 = *(const float4*)&pred[(size_t)(b*255 + a*85 + 4) * hw + pix];
      local += (fbce0(x4.x) + fbce0(x4.y) + fbce0(x4.z) + fbce0(x4.w)) * inv;
    }
    for (int off = 32; off > 0; off >>= 1) local += __shfl_xor(local, off, 64);
    __shared__ float red[16];
    if ((tid & 63) == 0) red[tid >> 6] = local;
    __syncthreads();
    if (tid == 0) {
      float t = 0.f;
      for (int k = 0; k < 16; ++k) t += red[k];
      partial[ob] = t;                    // plain store; k_final reads next dispatch
    }
  } else {
    // -------- correction role: LDS hash-set dedup, O(M) --------
    __shared__ int htab[HSIZE];
    __shared__ float cred[16];
    for (int k = tid; k < HSIZE; k += 1024) htab[k] = -1;
    __syncthreads();
    int M = 3 * N;
    float corr = 0.f;
    for (int i = tid; i < M; i += 1024) {
      int s = i / N, n = i - s * N;
      int w = (s == 0) ? 80 : ((s == 1) ? 40 : 20);
      float fw = (float)w;
      float gx = tgt[n*TCOLS + 2] * fw, gy = tgt[n*TCOLS + 3] * fw;
      if (gx >= 0.f && gx < fw && gy >= 0.f && gy < fw) {
        int hw = w * w;
        int gi = min(max((int)floorf(gx), 0), w - 1);
        int gj = min(max((int)floorf(gy), 0), w - 1);
        int b  = min(max((int)tgt[n*TCOLS + 0], 0), B - 1);
        int idx = b * hw + gj * w + gi;            // < 102400 < 2^17
        int key = (s << 17) | idx;
        unsigned h = ((unsigned)key * 2654435761u) >> 20;
        bool owner = false;
        for (;;) {
          int old = atomicCAS(&htab[h & (HSIZE-1)], -1, key);
          if (old == -1)  { owner = true; break; }
          if (old == key) { break; }
          ++h;
        }
        if (owner) {   // all 3 anchors of this distinct (s,b,cell)
          const float* pred = (s == 0) ? p0 : ((s == 1) ? p1 : p2);
          int cell = idx - b * hw;
          float inv = 1.f / (float)(B * 3 * hw);
          float sum = pred[(size_t)(b*255 +   4) * hw + cell]
                    + pred[(size_t)(b*255 +  89) * hw + cell]
                    + pred[(size_t)(b*255 + 174) * hw + cell];
          corr -= sum * inv;              // bce(x,1)-bce(x,0) = -x
        }
      }
    }
    for (int off = 32; off > 0; off >>= 1) corr += __shfl_xor(corr, off, 64);
    if ((tid & 63) == 0) cred[tid >> 6] = corr;
    __syncthreads();
    if (tid == 0) {
      float t = 0.f;
      for (int k = 0; k < 16; ++k) t += cred[k];
      acc[ACC_CORR] = t;                  // single writer, plain store
    }
  }
}

__global__ void k_final(const float* __restrict__ acc, const float* __restrict__ partial,
                        float* __restrict__ out) {
  __shared__ float slo;
  int t = threadIdx.x;                    // 128 threads
  float v = (t < OBJ_BLOCKS) ? partial[t] : 0.f;
  for (int off = 32; off > 0; off >>= 1) v += __shfl_xor(v, off, 64);
  if (t == 0) slo = v;                    // OBJ_BLOCKS < 64: wave 0 holds full sum
  __syncthreads();
  if (t == 0) {
    float lo = slo + acc[ACC_CORR];
    float lb = 0.f, lc = 0.f;
    for (int s = 0; s < 3; ++s) {
      float nv  = acc[ACC_NV(s)];
      float nvm = fmaxf(nv, 1.f);
      if (nv > 0.f) {
        lb += acc[ACC_BOX(s)] / nvm * 7.5f;                 // BOX_GAIN
        lc += acc[ACC_CLS(s)] / (nvm * (float)NC) * 0.5f;   // CLS_GAIN
      }
    }
    out[0] = lb + lc + lo;
    out[1] = lb;
    out[2] = lc;
    out[3] = lo;
  }
  if (t < NC) {
    float pc = 0.f;
    for (int s = 0; s < 3; ++s) {
      float cnt = acc[ACC_SEG + 3*NC + s*NC + t];
      if (cnt > 0.f)
        pc += acc[ACC_SEG + s*NC + t] / (fmaxf(cnt, 1.f) * (float)NC) * 0.5f;
    }
    out[4 + t] = pc;
  }
}

extern "C" void kernel_launch(void* const* d_in, const int* in_sizes, int n_in,
                              void* d_out, int out_size, void* d_ws, size_t ws_size,
                              hipStream_t stream) {
  const float* p0  = (const float*)d_in[0];
  const float* p1  = (const float*)d_in[1];
  const float* p2  = (const float*)d_in[2];
  const float* tgt = (const float*)d_in[3];
  int N = in_sizes[3] / TCOLS;             // 800 targets
  int B = in_sizes[0] / (255 * 6400);      // 16
  float* out = (float*)d_out;

  float* acc     = (float*)d_ws;
  float* partial = acc + ACC_TOTAL;        // OBJ_BLOCKS floats, written unconditionally

  int nrows = 9 * N;                       // 7200
  int RB = (nrows + 15) / 16;              // 450 rows-blocks
  int grid = RB + OBJ_BLOCKS + 1;          // 512 = 2 blocks/CU exactly

  k_init <<<1, 256, 0, stream>>>(acc);
  k_fused<<<grid, 1024, 0, stream>>>(p0, p1, p2, tgt, N, B, RB, acc, partial);
  k_final<<<1, 128, 0, stream>>>(acc, partial, out);
}

// Round 10
// 37.194 us; speedup vs baseline: 1.4018x; 1.1257x over previous
//
#include <hip/hip_runtime.h>
#include <math.h>

#define NC 80
#define TCOLS 6      // targets: [b, cls, x, y, w, h]
#define CORRB 40     // corr-scatter blocks
#define OBJB  22     // obj-stream blocks (40+22+450 = 512 = 2 blocks/CU)

// ANCHORS[scale][anchor][wh]
__device__ __constant__ float c_anch[3][3][2] = {
  {{10.f,13.f},{16.f,30.f},{33.f,23.f}},
  {{30.f,61.f},{62.f,45.f},{59.f,119.f}},
  {{116.f,90.f},{156.f,198.f},{373.f,326.f}}
};

// acc layout (floats) — each hot scalar on its own 64 B line
#define ACC_CORR   0                    // obj correction sum(-x/cnt)
#define ACC_BOX(s) (16 + 16*(s))
#define ACC_CLS(s) (64 + 16*(s))
#define ACC_NV(s)  (112 + 16*(s))
#define ACC_SEG    160                  // [3*NC sums][3*NC counts]
#define ACC_TOTAL  (160 + 6*NC)         // 640 floats

// fast transcendentals: v_exp/v_log/v_sqrt; abs err ~1e-6 << 0.47 threshold
__device__ __forceinline__ float fbce0(float x) {   // bce(x,0)
  return fmaxf(x, 0.f) + __logf(1.f + __expf(-fabsf(x)));
}
__device__ __forceinline__ float fbce(float x, float t) {
  return fmaxf(x, 0.f) - x * t + __logf(1.f + __expf(-fabsf(x)));
}
__device__ __forceinline__ float ffocal(float x, float t) {
  float ce = fbce(x, t);
  float u  = 1.f - __expf(-ce);
  return u * __builtin_amdgcn_sqrtf(u) * ce;        // (1-e^-ce)^1.5 * ce
}

__global__ void k_init(unsigned int* __restrict__ mask, int nwords,
                       float* __restrict__ acc) {
  int i  = blockIdx.x * blockDim.x + threadIdx.x;
  int st = gridDim.x * blockDim.x;
  for (int k = i; k < nwords;    k += st) mask[k] = 0u;
  for (int k = i; k < ACC_TOTAL; k += st) acc[k]  = 0.f;
}

// blocks [0, CORRB):            corr — bitmask dedup, owner accumulates -x/cnt
// blocks [CORRB, CORRB+OBJB):   obj background stream -> per-block partial stores
// blocks [CORRB+OBJB, ...):     rows — one 64-lane wave per (scale,target,anchor)
__global__ __launch_bounds__(1024, 8)
void k_fused(const float* __restrict__ p0, const float* __restrict__ p1,
             const float* __restrict__ p2, const float* __restrict__ tgt,
             unsigned int* __restrict__ mask, int N, int B,
             float* __restrict__ acc, float* __restrict__ partial) {
  const int bid = blockIdx.x;
  const int tid = threadIdx.x;
  __shared__ float red[16];
  __shared__ float l_box[3], l_cls[3], l_nv[3];

  if (bid >= CORRB + OBJB) {
    // ---------------- rows role ----------------
    if (tid < 3) { l_box[tid]=0.f; l_cls[tid]=0.f; l_nv[tid]=0.f; }
    __syncthreads();
    int row   = (bid - CORRB - OBJB) * 16 + (tid >> 6);
    int lane  = tid & 63;
    int nrows = 9 * N;
    if (row < nrows) {
      int rps = N * 3;
      int s   = row / rps;
      int rem = row - s * rps;
      int n   = rem / 3;
      int a   = rem - n * 3;
      int w   = (s == 0) ? 80 : ((s == 1) ? 40 : 20);
      int hw  = w * w;
      const float* pred = (s == 0) ? p0 : ((s == 1) ? p1 : p2);
      float fw = (float)w;
      float gx = tgt[n*TCOLS + 2] * fw, gy = tgt[n*TCOLS + 3] * fw;
      if (gx >= 0.f && gx < fw && gy >= 0.f && gy < fw) {   // wave-uniform
        float gw = tgt[n*TCOLS + 4] * fw, gh = tgt[n*TCOLS + 5] * fw;
        int gi  = min(max((int)floorf(gx), 0), w - 1);
        int gj  = min(max((int)floorf(gy), 0), w - 1);
        int b   = min(max((int)tgt[n*TCOLS + 0], 0), B - 1);
        int cls = min(max((int)tgt[n*TCOLS + 1], 0), NC - 1);
        size_t base = (size_t)(b*255 + a*85) * hw + (size_t)(gj*w + gi);

        // issue all global loads up-front (MLP); predicate extra lanes
        float x0  = pred[base + (size_t)(5 + lane) * hw];                      // cls c = lane
        float x1  = (lane < 16) ? pred[base + (size_t)(69 + lane) * hw] : 0.f; // cls 64+lane
        float bxv = (lane < 4)  ? pred[base + (size_t)lane * hw] : 0.f;

        float rs = ffocal(x0, (lane == cls) ? 1.f : 0.f);
        if (lane < 16) rs += ffocal(x1, ((64 + lane) == cls) ? 1.f : 0.f);
        for (int off = 32; off > 0; off >>= 1) rs += __shfl_xor(rs, off, 64);

        float bx = __shfl(bxv, 0, 64), by = __shfl(bxv, 1, 64);
        float bw = __shfl(bxv, 2, 64), bh = __shfl(bxv, 3, 64);
        if (lane == 0) {
          float sx = 1.f/(1.f + __expf(-bx));
          float sy = 1.f/(1.f + __expf(-by));
          float sw = 1.f/(1.f + __expf(-bw));
          float sh = 1.f/(1.f + __expf(-bh));
          float px = sx*2.f - 0.5f, py = sy*2.f - 0.5f;
          float aw = c_anch[s][a][0], ah = c_anch[s][a][1];
          float pw = (sw*2.f)*(sw*2.f)*aw, ph = (sh*2.f)*(sh*2.f)*ah;
          float txf = gx - floorf(gx), tyf = gy - floorf(gy);
          // iou_cxcywh replicated (eps on heights + union only)
          float b1x1 = px - pw*0.5f, b1x2 = px + pw*0.5f;
          float b1y1 = py - ph*0.5f, b1y2 = py + ph*0.5f;
          float b2x1 = txf - gw*0.5f, b2x2 = txf + gw*0.5f;
          float b2y1 = tyf - gh*0.5f, b2y2 = tyf + gh*0.5f;
          float iw = fmaxf(fminf(b1x2, b2x2) - fmaxf(b1x1, b2x1), 0.f);
          float ih = fmaxf(fminf(b1y2, b2y2) - fmaxf(b1y1, b2y1), 0.f);
          float inter = iw * ih;
          float w1 = b1x2 - b1x1, h1 = b1y2 - b1y1 + 1e-7f;
          float w2 = b2x2 - b2x1, h2 = b2y2 - b2y1 + 1e-7f;
          float uni = w1*h1 + w2*h2 - inter + 1e-7f;
          float iou = inter / uni;

          atomicAdd(&l_box[s], 1.f - iou);
          atomicAdd(&l_cls[s], rs);
          atomicAdd(&l_nv[s],  1.f);
          atomicAdd(&acc[ACC_SEG +        s*NC + cls], rs);
          atomicAdd(&acc[ACC_SEG + 3*NC + s*NC + cls], 1.f);
        }
      }
    }
    __syncthreads();
    if (tid < 3) {
      int s = tid; float v;
      v = l_box[s]; if (v != 0.f) atomicAdd(&acc[ACC_BOX(s)], v);
      v = l_cls[s]; if (v != 0.f) atomicAdd(&acc[ACC_CLS(s)], v);
      v = l_nv [s]; if (v != 0.f) atomicAdd(&acc[ACC_NV (s)], v);
    }
  } else if (bid >= CORRB) {
    // ---------------- obj background stream role ----------------
    const int ob = bid - CORRB;
    const int n0 = B*3*6400, n1 = B*3*1600, n2 = B*3*400;
    const int total4 = (n0 + n1 + n2) >> 2;
    const float i0 = 1.f/(float)n0, i1 = 1.f/(float)n1, i2 = 1.f/(float)n2;
    float local = 0.f;
    for (int i = ob * 1024 + tid; i < total4; i += OBJB * 1024) {
      int e = i << 2;
      const float* pred; int idx, hw; float inv;
      if (e < n0)         { pred = p0; idx = e;           hw = 6400; inv = i0; }
      else if (e < n0+n1) { pred = p1; idx = e - n0;      hw = 1600; inv = i1; }
      else                { pred = p2; idx = e - n0 - n1; hw = 400;  inv = i2; }
      int ba = idx / hw, pix = idx - ba * hw;     // pix..pix+3 in-plane (hw%4==0)
      int b = ba / 3, a = ba - b * 3;
      const float4 x4 = *(const float4*)&pred[(size_t)(b*255 + a*85 + 4) * hw + pix];
      local += (fbce0(x4.x) + fbce0(x4.y) + fbce0(x4.z) + fbce0(x4.w)) * inv;
    }
    for (int off = 32; off > 0; off >>= 1) local += __shfl_xor(local, off, 64);
    if ((tid & 63) == 0) red[tid >> 6] = local;
    __syncthreads();
    if (tid == 0) {
      float t = 0.f;
      for (int k = 0; k < 16; ++k) t += red[k];
      partial[ob] = t;                    // plain store; k_final reads next dispatch
    }
  } else {
    // -------- corr role: bitmask dedup spread over CORRB blocks --------
    // item i = (n, s, a); atomicOr winner owns the bit and loads pobj once
    int i = bid * 1024 + tid;             // CORRB*1024 = 40960 >= 9N = 7200
    float corr = 0.f;
    int M = 9 * N;
    if (i < M) {
      int n = i / 9, r = i - n * 9;
      int s = r / 3, a = r - s * 3;
      int w = (s == 0) ? 80 : ((s == 1) ? 40 : 20);
      float fw = (float)w;
      float gx = tgt[n*TCOLS + 2] * fw, gy = tgt[n*TCOLS + 3] * fw;
      if (gx >= 0.f && gx < fw && gy >= 0.f && gy < fw) {
        int hw = w * w;
        int gi = min(max((int)floorf(gx), 0), w - 1);
        int gj = min(max((int)floorf(gy), 0), w - 1);
        int b  = min(max((int)tgt[n*TCOLS + 0], 0), B - 1);
        int basebit = (s == 0) ? 0 : ((s == 1) ? B*3*6400 : B*3*8000);
        int bit = basebit + (b*3 + a)*hw + gj*w + gi;
        unsigned int m = 1u << (bit & 31);
        unsigned int old = atomicOr(&mask[bit >> 5], m);
        if (!(old & m)) {                 // newly set -> owner
          const float* pred = (s == 0) ? p0 : ((s == 1) ? p1 : p2);
          float x = pred[(size_t)(b*255 + a*85 + 4) * hw + (size_t)(gj*w + gi)];
          corr -= x / (float)(B * 3 * hw);   // bce(x,1)-bce(x,0) = -x
        }
      }
    }
    for (int off = 32; off > 0; off >>= 1) corr += __shfl_xor(corr, off, 64);
    if ((tid & 63) == 0) red[tid >> 6] = corr;
    __syncthreads();
    if (tid == 0) {
      float t = 0.f;
      for (int k = 0; k < 16; ++k) t += red[k];
      if (t != 0.f) atomicAdd(&acc[ACC_CORR], t);
    }
  }
}

__global__ void k_final(const float* __restrict__ acc, const float* __restrict__ partial,
                        float* __restrict__ out) {
  __shared__ float slo;
  int t = threadIdx.x;                    // 128 threads
  float v = (t < OBJB) ? partial[t] : 0.f;
  for (int off = 32; off > 0; off >>= 1) v += __shfl_xor(v, off, 64);
  if (t == 0) slo = v;                    // OBJB < 64: wave 0 holds full sum
  __syncthreads();
  if (t == 0) {
    float lo = slo + acc[ACC_CORR];
    float lb = 0.f, lc = 0.f;
    for (int s = 0; s < 3; ++s) {
      float nv  = acc[ACC_NV(s)];
      float nvm = fmaxf(nv, 1.f);
      if (nv > 0.f) {
        lb += acc[ACC_BOX(s)] / nvm * 7.5f;                 // BOX_GAIN
        lc += acc[ACC_CLS(s)] / (nvm * (float)NC) * 0.5f;   // CLS_GAIN
      }
    }
    out[0] = lb + lc + lo;
    out[1] = lb;
    out[2] = lc;
    out[3] = lo;
  }
  if (t < NC) {
    float pc = 0.f;
    for (int s = 0; s < 3; ++s) {
      float cnt = acc[ACC_SEG + 3*NC + s*NC + t];
      if (cnt > 0.f)
        pc += acc[ACC_SEG + s*NC + t] / (fmaxf(cnt, 1.f) * (float)NC) * 0.5f;
    }
    out[4 + t] = pc;
  }
}

extern "C" void kernel_launch(void* const* d_in, const int* in_sizes, int n_in,
                              void* d_out, int out_size, void* d_ws, size_t ws_size,
                              hipStream_t stream) {
  const float* p0  = (const float*)d_in[0];
  const float* p1  = (const float*)d_in[1];
  const float* p2  = (const float*)d_in[2];
  const float* tgt = (const float*)d_in[3];
  int N = in_sizes[3] / TCOLS;             // 800 targets
  int B = in_sizes[0] / (255 * 6400);      // 16
  float* out = (float*)d_out;

  unsigned int* mask = (unsigned int*)d_ws;
  int nbits  = B * 3 * (6400 + 1600 + 400);            // 403,200 tobj cells
  int nwords = (nbits + 31) / 32;                      // 12,600 words (50.4 KB)
  float* acc     = (float*)((char*)d_ws + (((size_t)nwords * 4 + 255) & ~(size_t)255));
  float* partial = acc + ACC_TOTAL;                    // OBJB floats, unconditional

  int nrows = 9 * N;                       // 7200
  int RB = (nrows + 15) / 16;              // 450 rows-blocks
  int grid = CORRB + OBJB + RB;            // 512 = 2 blocks/CU exactly

  k_init <<<64, 256, 0, stream>>>(mask, nwords, acc);
  k_fused<<<grid, 1024, 0, stream>>>(p0, p1, p2, tgt, mask, N, B, acc, partial);
  k_final<<<1, 128, 0, stream>>>(acc, partial, out);
}